// Round 9
// baseline (152.927 us; speedup 1.0000x reference)
//
#include <hip/hip_runtime.h>
#include <hip/hip_fp16.h>

// EncoderDecoderLSTM fused kernel for MI355X (gfx950).
//
// Math: state never updates, h0=c0=0  =>
//   gates = input @ (W_ih @ enc_W)^T + (W_ih @ enc_b + b_ih + b_hh)
//   f-gate is dead (multiplies c0=0). Only i,g,o needed (768 of 1024 rows).
//
// prep2 pre-scales fused weights so MFMA emits exp2-ready gate values:
//     i,o rows x (-log2 e),  g rows x (2 log2 e)
//   U = exp2(iv), E = exp2(gv), Uo = exp2(ov)   (f32 exp2, exact args)
//   SEPARATE packed-f16 reciprocals (v_rcp_f16):
//     sigma(i) = rcp(1+U), tanh(g) = 1 - 2*rcp(1+E), sigma(o) = rcp(1+Uo)
//   Every f16 infinity is a TRUE saturation: U->inf => c=0; E->inf =>
//   tanh=1; O->inf => h=0. No clamps anywhere.
//   tanh(c) via degree-11 odd poly, |c|<=1 -- PACKED f16
//   h = sigma(o) * tanh(c);  out = h @ dec_W^T + dec_b
//
// Round-9 fix of round-8 FAIL (absmax 0.104): merging denominators
// (1+U)(1+E) in f16 overflows at U>=0.07, E~2^15.9 -> rcp(inf)=0 zeroed a
// LIVE c~0.9. Unmerged rcps cannot hit that: each factor's inf is a real
// gate saturation with exact limit. Trans/pair 12 -> 9, plain 18 -> 16.
//
// Round-6/7: LDS h-handoff eliminated via k-slot co-permutation of decWb
// and the activation output (MFMA k-sum is permutation-invariant).
// Round-5: 1-deep pipeline REGRESSED (VGPR 64->80) -- VGPR must stay <= 64.
// Round-4: packed-f16 poly tail (SIMD-32: f16x2 halves lane-cycles).
// Round-3: only 2048 unique t rows (future rows = copies of t=2047);
//   2048 blocks = exactly 8/CU, t0=2016 wave fans out the duplicates.
//
// prep2: block-per-row parallel weight fusion (768 rows, 32-iter loops).
// lstm_main: per-wave 32 rows, f16 MFMA 16x16x32; biases ride the MFMA C
//   operand; activation output feeds the decoder MFMA directly in registers.

typedef _Float16 f16x8 __attribute__((ext_vector_type(8)));
typedef _Float16 f16x4 __attribute__((ext_vector_type(4)));
typedef _Float16 f16x2 __attribute__((ext_vector_type(2)));
typedef float    f32x4 __attribute__((ext_vector_type(4)));
typedef float    f32x2 __attribute__((ext_vector_type(2)));
typedef __fp16   h16x2 __attribute__((ext_vector_type(2)));

#define T_IN 2048
#define TT   2112   // T + future_n
#define FIN  32
#define FOUT 32

// ws layout (bytes): Mb @0 (49152), fb @49152 (3072), decWb @52224 (16384)
#define WS_FB_OFF   49152
#define WS_DECW_OFF 52224

union PkU { h16x2 h; f16x2 f; unsigned u; };
union H2U { __half2 hh; f16x2 f; unsigned u; };
union B2U { f16x8 v; unsigned u[4]; };

__global__ __launch_bounds__(256) void prep2(
    const float* __restrict__ enc_W, const float* __restrict__ enc_b,
    const float* __restrict__ W_ih, const float* __restrict__ b_ih,
    const float* __restrict__ b_hh, const float* __restrict__ dec_W,
    _Float16* __restrict__ Mb, float* __restrict__ fb, _Float16* __restrict__ decWb) {
    const int blk = blockIdx.x;
    const int tid = threadIdx.x;
    if (blk < 768) {
        // row gg: 0-255 = i (sg=gg), 256-511 = g (sg=gg+256), 512-767 = o
        const int gg = blk, sg = gg + (gg >= 256 ? 256 : 0);
        // exp2-ready prescale: i,o rows * -log2(e); g rows * 2*log2(e)
        const float SCL = (gg >= 256 && gg < 512) ?  2.8853900817779268f
                                                  : -1.4426950408889634f;
        const float* wr = W_ih + (size_t)sg * 256;
        const int f = tid & 31, r8 = tid >> 5;
        float acc = 0.f;
#pragma unroll
        for (int k = 0; k < 32; ++k) {
            int r = r8 * 32 + k;
            acc = fmaf(wr[r], enc_W[r * 32 + f], acc);
        }
        __shared__ float red[256];
        __shared__ float redb[256];
        __shared__ float red2[32];
        red[tid]  = acc;
        redb[tid] = wr[tid] * enc_b[tid];
        __syncthreads();
        if (tid < 32) {
            float s = 0.f;
#pragma unroll
            for (int k = 0; k < 8; ++k) s += red[k * 32 + tid];
            Mb[gg * 32 + tid] = (_Float16)(s * SCL);
        } else if (tid >= 128 && tid < 160) {
            int t2 = tid - 128;
            float s2 = 0.f;
#pragma unroll
            for (int k = 0; k < 8; ++k) s2 += redb[t2 * 8 + k];
            red2[t2] = s2;
        }
        __syncthreads();
        if (tid == 0) {
            float t = b_ih[sg] + b_hh[sg];
#pragma unroll
            for (int k = 0; k < 32; ++k) t += red2[k];
            fb[gg] = t * SCL;
        }
    } else {
        // blocks 768..775: dec_W f32 -> f16, PERMUTED within each 32-hid
        // block so the decoder B-operand is the activation output in its
        // natural register order: slot (q*8+j) <- hid (j<4 ? 4q+j
        // : 16+4q+j-4). Each thread's 4 slots map to 4 CONTIGUOUS source
        // hids, so the f32x4 load survives.
        int i  = (blk - 768) * 1024 + tid * 4;   // 4 consecutive slots
        int od = i >> 8, s = i & 255;
        int hb = s & 224, s32 = s & 31;
        int q  = s32 >> 3;
        int src = od * 256 + hb + 4 * q + ((s32 & 4) ? 16 : 0);
        f32x4 v = *(const f32x4*)(dec_W + src);
        f16x4 o;
#pragma unroll
        for (int j = 0; j < 4; ++j) o[j] = (_Float16)v[j];
        *(f16x4*)(decWb + i) = o;
    }
}

// Activation for a PAIR of adjacent h-values. f32 exp2 front-end (exact
// args), SEPARATE packed-f16 reciprocals (every inf = true saturation,
// no clamps), packed-f16 poly tail. Returns packed f16x2 h as a u32.
__device__ __forceinline__ unsigned act_pair(f32x2 iv, f32x2 gv, f32x2 ov) {
    float U0 = __builtin_amdgcn_exp2f(iv.x), U1 = __builtin_amdgcn_exp2f(iv.y);
    float E0 = __builtin_amdgcn_exp2f(gv.x), E1 = __builtin_amdgcn_exp2f(gv.y);
    float O0 = __builtin_amdgcn_exp2f(ov.x), O1 = __builtin_amdgcn_exp2f(ov.y);
    PkU Uu, Eu, Ou;
    Uu.h = __builtin_amdgcn_cvt_pkrtz(U0, U1);   // inf -> sigma(i)=0 exact
    Eu.h = __builtin_amdgcn_cvt_pkrtz(E0, E1);   // inf -> tanh(g)=1 exact
    Ou.h = __builtin_amdgcn_cvt_pkrtz(O0, O1);   // inf -> h=0 exact
    const _Float16 one = (_Float16)1.0f;
    H2U aU, aE, aO, rU, rE, rO;
    aU.f = Uu.f + one;
    aE.f = Eu.f + one;
    aO.f = Ou.f + one;
    rU.hh = h2rcp(aU.hh);                 // sigma(i)
    rE.hh = h2rcp(aE.hh);
    rO.hh = h2rcp(aO.hh);                 // sigma(o)
    f16x2 th  = one - (_Float16)2.0f * rE.f;   // tanh(g)
    f16x2 c16 = th * rU.f;                     // sigma(i)*tanh(g), |c|<=1
    // tanh(c): odd poly in packed f16
    f16x2 z  = c16 * c16;
    f16x2 cz = c16 * z;
    f16x2 P  = z * (_Float16)(-5.70498872745e-3f) + (_Float16)(2.06390887954e-2f);
    P = z * P + (_Float16)(-5.37397155531e-2f);
    P = z * P + (_Float16)(1.33314422036e-1f);
    P = z * P + (_Float16)(-3.33332819422e-1f);
    f16x2 tc = cz * P + c16;              // tanh(c)
    PkU r; r.f = rO.f * tc;               // h = sigma(o)*tanh(c)
    return r.u;
}

__global__ __launch_bounds__(256) void lstm_main(
    const float* __restrict__ in, const _Float16* __restrict__ Mb,
    const float* __restrict__ fb, const _Float16* __restrict__ decWb,
    const float* __restrict__ dec_b, float* __restrict__ out) {
    // tiny per-wave broadcast buffer (future-row fan-out only)
    __shared__ float fbc[4][32];

    const int lane = threadIdx.x & 63;
    const int w    = threadIdx.x >> 6;
    const int l16  = lane & 15;
    const int q    = lane >> 4;
    const int wave = blockIdx.x * 4 + w;      // 0..8191
    const int b    = wave >> 6;                // 64 waves per batch row
    const int t0   = (wave & 63) * 32;         // 0..2016 (unique rows only)

    // Input B-fragments: B[k=q*8+j][n=l16] = input[b][t][q*8+j]  (t < 2048)
    f16x8 bfr[2];
#pragma unroll
    for (int s = 0; s < 2; ++s) {
        int t  = t0 + s * 16 + l16;
        const float* p = in + ((size_t)(b * T_IN + t)) * FIN + q * 8;
        f32x4 u0 = *(const f32x4*)(p);
        f32x4 u1 = *(const f32x4*)(p + 4);
        f16x8 v;
#pragma unroll
        for (int j = 0; j < 4; ++j) { v[j] = (_Float16)u0[j]; v[4 + j] = (_Float16)u1[j]; }
        bfr[s] = v;
    }

    // decoder acc starts at dec_b (rides the MFMA C operand)
    f32x4 dacc[2][2];
#pragma unroll
    for (int ot = 0; ot < 2; ++ot) {
        f32x4 db = *(const f32x4*)(dec_b + ot * 16 + q * 4);
        dacc[0][ot] = db; dacc[1][ot] = db;
    }

    for (int hc = 0; hc < 8; ++hc) {
        const int hb = hc * 32;
        // Gate weight A-frags + bias C-frags
        f16x8 afr[3][2];
        f32x4 fbv[3][2];
#pragma unroll
        for (int gt = 0; gt < 3; ++gt)
#pragma unroll
            for (int X = 0; X < 2; ++X) {
                int grow = gt * 256 + hb + X * 16;
                afr[gt][X] = *(const f16x8*)(Mb + (size_t)(grow + l16) * 32 + q * 8);
                fbv[gt][X] = *(const f32x4*)(fb + grow + q * 4);
            }
        // Decoder A-frags (hid-permuted layout): A2[m=ot*16+l16][slot q*8+j]
        f16x8 a2[2];
#pragma unroll
        for (int ot = 0; ot < 2; ++ot)
            a2[ot] = *(const f16x8*)(decWb + (size_t)(ot * 16 + l16) * 256 + hb + q * 8);

#pragma unroll
        for (int s = 0; s < 2; ++s) {
            // D[m = gate hid][n = t]; bias pre-loaded as C operand.
            // Values arrive pre-scaled: exp2-ready.
            f32x4 gi[2], gg[2], go[2];
#pragma unroll
            for (int X = 0; X < 2; ++X) {
                gi[X] = __builtin_amdgcn_mfma_f32_16x16x32_f16(afr[0][X], bfr[s], fbv[0][X], 0, 0, 0);
                gg[X] = __builtin_amdgcn_mfma_f32_16x16x32_f16(afr[1][X], bfr[s], fbv[1][X], 0, 0, 0);
                go[X] = __builtin_amdgcn_mfma_f32_16x16x32_f16(afr[2][X], bfr[s], fbv[2][X], 0, 0, 0);
            }
            // Activation output in production order IS the decoder B-frag
            // (decWb slot permutation): elems 0..3 = X=0 r=0..3 (hid 4q+r),
            // elems 4..7 = X=1 r=0..3 (hid 16+4q+r).
            B2U b2u;
#pragma unroll
            for (int X = 0; X < 2; ++X) {
                f32x2 i01 = { gi[X][0], gi[X][1] }, i23 = { gi[X][2], gi[X][3] };
                f32x2 g01 = { gg[X][0], gg[X][1] }, g23 = { gg[X][2], gg[X][3] };
                f32x2 o01 = { go[X][0], go[X][1] }, o23 = { go[X][2], go[X][3] };
                b2u.u[X * 2 + 0] = act_pair(i01, g01, o01);
                b2u.u[X * 2 + 1] = act_pair(i23, g23, o23);
            }
#pragma unroll
            for (int ot = 0; ot < 2; ++ot)
                dacc[s][ot] = __builtin_amdgcn_mfma_f32_16x16x32_f16(a2[ot], b2u.v, dacc[s][ot], 0, 0, 0);
        }
    }

    // D2[od = ot*16 + 4q + r][t=l16] -> out[(b*TT+t)*32 + od], float4 per lane
#pragma unroll
    for (int s = 0; s < 2; ++s) {
        int t = t0 + s * 16 + l16;
        size_t ro = ((size_t)(b * TT + t)) * FOUT;
#pragma unroll
        for (int ot = 0; ot < 2; ++ot)
            *(f32x4*)(out + ro + ot * 16 + q * 4) = dacc[s][ot];
    }

    // Future rows 2048..2111 are copies of row 2047 (held by lanes l16==15
    // of the wave with t0==2016). Broadcast that row wave-internally via LDS,
    // then all 64 lanes fan the 64 duplicate rows out.
    if ((wave & 63) == 63) {
        float* fo = &fbc[w][0];
        if (l16 == 15) {
            *(f32x4*)(fo + q * 4)      = dacc[1][0];
            *(f32x4*)(fo + 16 + q * 4) = dacc[1][1];
        }
        asm volatile("s_waitcnt lgkmcnt(0)" ::: "memory");
        f32x4 r0 = *(const f32x4*)(fo + q * 4);
        f32x4 r1 = *(const f32x4*)(fo + 16 + q * 4);
#pragma unroll
        for (int fg = 0; fg < 4; ++fg) {
            int t = T_IN + fg * 16 + l16;
            size_t ro = ((size_t)(b * TT + t)) * FOUT;
            *(f32x4*)(out + ro + q * 4)      = r0;
            *(f32x4*)(out + ro + 16 + q * 4) = r1;
        }
    }
}

extern "C" void kernel_launch(void* const* d_in, const int* in_sizes, int n_in,
                              void* d_out, int out_size, void* d_ws, size_t ws_size,
                              hipStream_t stream) {
    const float* input = (const float*)d_in[0];
    const float* enc_W = (const float*)d_in[1];
    const float* enc_b = (const float*)d_in[2];
    const float* W_ih  = (const float*)d_in[3];
    // d_in[4] = W_hh: unused (h0 = 0 -> state_gates = b_hh only)
    const float* b_ih  = (const float*)d_in[5];
    const float* b_hh  = (const float*)d_in[6];
    const float* dec_W = (const float*)d_in[7];
    const float* dec_b = (const float*)d_in[8];
    // d_in[9] = future_n (fixed 64, baked into TT)

    _Float16* Mb    = (_Float16*)d_ws;
    float*    fb    = (float*)((char*)d_ws + WS_FB_OFF);
    _Float16* decWb = (_Float16*)((char*)d_ws + WS_DECW_OFF);
    float*    out   = (float*)d_out;

    prep2<<<776, 256, 0, stream>>>(enc_W, enc_b, W_ih, b_ih, b_hh, dec_W, Mb, fb, decWb);
    // 128 b * 2048 unique t rows / 32 rows-per-wave = 8192 waves; 4 waves/block
    // = 2048 blocks = exactly 8 blocks/CU (perfect balance)
    lstm_main<<<2048, 256, 0, stream>>>(input, Mb, fb, decWb, dec_b, out);
}

// Round 10
// 150.819 us; speedup vs baseline: 1.0140x; 1.0140x over previous
//
#include <hip/hip_runtime.h>

// EncoderDecoderLSTM fused kernel for MI355X (gfx950).
//
// Math: state never updates, h0=c0=0  =>
//   gates = input @ (W_ih @ enc_W)^T + (W_ih @ enc_b + b_ih + b_hh)
//   f-gate is dead (multiplies c0=0). Only i,g,o needed (768 of 1024 rows).
//
// prep2 pre-scales fused weights so MFMA emits exp2-ready gate values:
//     i,o rows x (-log2 e),  g rows x (2 log2 e)
//   U = exp2(iv), E = exp2(min(gv,86.5)), O = exp2(ov)   (f32, exact args)
//   MERGED denominator, f32 rcps (10 trans/pair, the known minimum):
//     d = (1+U)(1+E) = fma(E, 1+U, 1+U);  R = rcp(d)
//     c = (E-1)/d    = fma(E, R, -R)      (all saturations exact in f32:
//       U=inf -> R=0 -> c=0; E=0 -> c=-R=-sigma(i); d-ovf -> true c<2^-41)
//     sigma(o) = rcp(1+O)
//   tanh(c) via degree-11 odd poly, |c|<=1 -- PACKED f16
//   h = sigma(o) * tanh(c);  out = h @ dec_W^T + dec_b
//
// Round-10: clean A/B after round-9's audit. h2rcp is NOT packed (2x
// v_rcp_f16), so R7 and R9 were BOTH 12 trans/pair; R9's f16-rcp shuffle
// cost +2.2us. This round puts the 10-trans merged act (R4's math, fma-
// folded) onto the no-LDS structure: -2 trans/pair at equal plain count.
// Readout: >=69us => trans count isn't the limiter; declare dep-floor.
//
// Round-8 FAIL lesson: merged denominator OVERFLOWS IN F16 (65504) for
// live values -- merge is f32-only, with the g-clamp keeping E finite.
// Round-6/7: LDS h-handoff eliminated via k-slot co-permutation of decWb
// and the activation output (MFMA k-sum is permutation-invariant).
// Round-5: 1-deep pipeline REGRESSED (VGPR 64->80) -- VGPR must stay <= 64.
// Round-4: packed-f16 poly tail (SIMD-32: f16x2 halves lane-cycles).
// Round-3: only 2048 unique t rows (future rows = copies of t=2047);
//   2048 blocks = exactly 8/CU, t0=2016 wave fans out the duplicates.
//
// prep2: block-per-row parallel weight fusion (768 rows, 32-iter loops).
// lstm_main: per-wave 32 rows, f16 MFMA 16x16x32; biases ride the MFMA C
//   operand; activation output feeds the decoder MFMA directly in registers.

typedef _Float16 f16x8 __attribute__((ext_vector_type(8)));
typedef _Float16 f16x4 __attribute__((ext_vector_type(4)));
typedef _Float16 f16x2 __attribute__((ext_vector_type(2)));
typedef float    f32x4 __attribute__((ext_vector_type(4)));
typedef float    f32x2 __attribute__((ext_vector_type(2)));
typedef __fp16   h16x2 __attribute__((ext_vector_type(2)));

#define T_IN 2048
#define TT   2112   // T + future_n
#define FIN  32
#define FOUT 32

// ws layout (bytes): Mb @0 (49152), fb @49152 (3072), decWb @52224 (16384)
#define WS_FB_OFF   49152
#define WS_DECW_OFF 52224

union PkU { h16x2 h; f16x2 f; unsigned u; };
union B2U { f16x8 v; unsigned u[4]; };

__global__ __launch_bounds__(256) void prep2(
    const float* __restrict__ enc_W, const float* __restrict__ enc_b,
    const float* __restrict__ W_ih, const float* __restrict__ b_ih,
    const float* __restrict__ b_hh, const float* __restrict__ dec_W,
    _Float16* __restrict__ Mb, float* __restrict__ fb, _Float16* __restrict__ decWb) {
    const int blk = blockIdx.x;
    const int tid = threadIdx.x;
    if (blk < 768) {
        // row gg: 0-255 = i (sg=gg), 256-511 = g (sg=gg+256), 512-767 = o
        const int gg = blk, sg = gg + (gg >= 256 ? 256 : 0);
        // exp2-ready prescale: i,o rows * -log2(e); g rows * 2*log2(e)
        const float SCL = (gg >= 256 && gg < 512) ?  2.8853900817779268f
                                                  : -1.4426950408889634f;
        const float* wr = W_ih + (size_t)sg * 256;
        const int f = tid & 31, r8 = tid >> 5;
        float acc = 0.f;
#pragma unroll
        for (int k = 0; k < 32; ++k) {
            int r = r8 * 32 + k;
            acc = fmaf(wr[r], enc_W[r * 32 + f], acc);
        }
        __shared__ float red[256];
        __shared__ float redb[256];
        __shared__ float red2[32];
        red[tid]  = acc;
        redb[tid] = wr[tid] * enc_b[tid];
        __syncthreads();
        if (tid < 32) {
            float s = 0.f;
#pragma unroll
            for (int k = 0; k < 8; ++k) s += red[k * 32 + tid];
            Mb[gg * 32 + tid] = (_Float16)(s * SCL);
        } else if (tid >= 128 && tid < 160) {
            int t2 = tid - 128;
            float s2 = 0.f;
#pragma unroll
            for (int k = 0; k < 8; ++k) s2 += redb[t2 * 8 + k];
            red2[t2] = s2;
        }
        __syncthreads();
        if (tid == 0) {
            float t = b_ih[sg] + b_hh[sg];
#pragma unroll
            for (int k = 0; k < 32; ++k) t += red2[k];
            fb[gg] = t * SCL;
        }
    } else {
        // blocks 768..775: dec_W f32 -> f16, PERMUTED within each 32-hid
        // block so the decoder B-operand is the activation output in its
        // natural register order: slot (q*8+j) <- hid (j<4 ? 4q+j
        // : 16+4q+j-4). Each thread's 4 slots map to 4 CONTIGUOUS source
        // hids, so the f32x4 load survives.
        int i  = (blk - 768) * 1024 + tid * 4;   // 4 consecutive slots
        int od = i >> 8, s = i & 255;
        int hb = s & 224, s32 = s & 31;
        int q  = s32 >> 3;
        int src = od * 256 + hb + 4 * q + ((s32 & 4) ? 16 : 0);
        f32x4 v = *(const f32x4*)(dec_W + src);
        f16x4 o;
#pragma unroll
        for (int j = 0; j < 4; ++j) o[j] = (_Float16)v[j];
        *(f16x4*)(decWb + i) = o;
    }
}

// Activation for a PAIR of adjacent h-values. f32 front-end with MERGED
// denominator (10 trans/pair: 6 exp2 + 4 rcp), fma-folded; packed-f16
// poly tail. Returns packed f16x2 h as a u32.
__device__ __forceinline__ unsigned act_pair(f32x2 iv, f32x2 gv, f32x2 ov) {
    float U0 = __builtin_amdgcn_exp2f(iv.x), U1 = __builtin_amdgcn_exp2f(iv.y);
    float g0 = fminf(gv.x, 86.5f),           g1 = fminf(gv.y, 86.5f);
    float E0 = __builtin_amdgcn_exp2f(g0),   E1 = __builtin_amdgcn_exp2f(g1);
    float O0 = __builtin_amdgcn_exp2f(ov.x), O1 = __builtin_amdgcn_exp2f(ov.y);
    float aU0 = 1.0f + U0,                   aU1 = 1.0f + U1;
    float d0  = fmaf(E0, aU0, aU0),          d1  = fmaf(E1, aU1, aU1);  // (1+U)(1+E)
    float R0  = __builtin_amdgcn_rcpf(d0),   R1  = __builtin_amdgcn_rcpf(d1);
    float c0  = fmaf(E0, R0, -R0),           c1  = fmaf(E1, R1, -R1);   // (E-1)/d
    float aO0 = 1.0f + O0,                   aO1 = 1.0f + O1;
    float s0  = __builtin_amdgcn_rcpf(aO0),  s1  = __builtin_amdgcn_rcpf(aO1);
    // ---- packed f16 tail ----
    PkU cu; cu.h = __builtin_amdgcn_cvt_pkrtz(c0, c1);
    PkU su; su.h = __builtin_amdgcn_cvt_pkrtz(s0, s1);   // sigma(o)
    f16x2 c16 = cu.f, so = su.f;
    f16x2 z  = c16 * c16;
    f16x2 cz = c16 * z;
    f16x2 P  = z * (_Float16)(-5.70498872745e-3f) + (_Float16)(2.06390887954e-2f);
    P = z * P + (_Float16)(-5.37397155531e-2f);
    P = z * P + (_Float16)(1.33314422036e-1f);
    P = z * P + (_Float16)(-3.33332819422e-1f);
    f16x2 tc = cz * P + c16;              // tanh(c)
    PkU r; r.f = so * tc;                 // h = sigma(o)*tanh(c)
    return r.u;
}

__global__ __launch_bounds__(256) void lstm_main(
    const float* __restrict__ in, const _Float16* __restrict__ Mb,
    const float* __restrict__ fb, const _Float16* __restrict__ decWb,
    const float* __restrict__ dec_b, float* __restrict__ out) {
    // tiny per-wave broadcast buffer (future-row fan-out only)
    __shared__ float fbc[4][32];

    const int lane = threadIdx.x & 63;
    const int w    = threadIdx.x >> 6;
    const int l16  = lane & 15;
    const int q    = lane >> 4;
    const int wave = blockIdx.x * 4 + w;      // 0..8191
    const int b    = wave >> 6;                // 64 waves per batch row
    const int t0   = (wave & 63) * 32;         // 0..2016 (unique rows only)

    // Input B-fragments: B[k=q*8+j][n=l16] = input[b][t][q*8+j]  (t < 2048)
    f16x8 bfr[2];
#pragma unroll
    for (int s = 0; s < 2; ++s) {
        int t  = t0 + s * 16 + l16;
        const float* p = in + ((size_t)(b * T_IN + t)) * FIN + q * 8;
        f32x4 u0 = *(const f32x4*)(p);
        f32x4 u1 = *(const f32x4*)(p + 4);
        f16x8 v;
#pragma unroll
        for (int j = 0; j < 4; ++j) { v[j] = (_Float16)u0[j]; v[4 + j] = (_Float16)u1[j]; }
        bfr[s] = v;
    }

    // decoder acc starts at dec_b (rides the MFMA C operand)
    f32x4 dacc[2][2];
#pragma unroll
    for (int ot = 0; ot < 2; ++ot) {
        f32x4 db = *(const f32x4*)(dec_b + ot * 16 + q * 4);
        dacc[0][ot] = db; dacc[1][ot] = db;
    }

    for (int hc = 0; hc < 8; ++hc) {
        const int hb = hc * 32;
        // Gate weight A-frags + bias C-frags
        f16x8 afr[3][2];
        f32x4 fbv[3][2];
#pragma unroll
        for (int gt = 0; gt < 3; ++gt)
#pragma unroll
            for (int X = 0; X < 2; ++X) {
                int grow = gt * 256 + hb + X * 16;
                afr[gt][X] = *(const f16x8*)(Mb + (size_t)(grow + l16) * 32 + q * 8);
                fbv[gt][X] = *(const f32x4*)(fb + grow + q * 4);
            }
        // Decoder A-frags (hid-permuted layout): A2[m=ot*16+l16][slot q*8+j]
        f16x8 a2[2];
#pragma unroll
        for (int ot = 0; ot < 2; ++ot)
            a2[ot] = *(const f16x8*)(decWb + (size_t)(ot * 16 + l16) * 256 + hb + q * 8);

#pragma unroll
        for (int s = 0; s < 2; ++s) {
            // D[m = gate hid][n = t]; bias pre-loaded as C operand.
            // Values arrive pre-scaled: exp2-ready.
            f32x4 gi[2], gg[2], go[2];
#pragma unroll
            for (int X = 0; X < 2; ++X) {
                gi[X] = __builtin_amdgcn_mfma_f32_16x16x32_f16(afr[0][X], bfr[s], fbv[0][X], 0, 0, 0);
                gg[X] = __builtin_amdgcn_mfma_f32_16x16x32_f16(afr[1][X], bfr[s], fbv[1][X], 0, 0, 0);
                go[X] = __builtin_amdgcn_mfma_f32_16x16x32_f16(afr[2][X], bfr[s], fbv[2][X], 0, 0, 0);
            }
            // Activation output in production order IS the decoder B-frag
            // (decWb slot permutation): elems 0..3 = X=0 r=0..3 (hid 4q+r),
            // elems 4..7 = X=1 r=0..3 (hid 16+4q+r).
            B2U b2u;
#pragma unroll
            for (int X = 0; X < 2; ++X) {
                f32x2 i01 = { gi[X][0], gi[X][1] }, i23 = { gi[X][2], gi[X][3] };
                f32x2 g01 = { gg[X][0], gg[X][1] }, g23 = { gg[X][2], gg[X][3] };
                f32x2 o01 = { go[X][0], go[X][1] }, o23 = { go[X][2], go[X][3] };
                b2u.u[X * 2 + 0] = act_pair(i01, g01, o01);
                b2u.u[X * 2 + 1] = act_pair(i23, g23, o23);
            }
#pragma unroll
            for (int ot = 0; ot < 2; ++ot)
                dacc[s][ot] = __builtin_amdgcn_mfma_f32_16x16x32_f16(a2[ot], b2u.v, dacc[s][ot], 0, 0, 0);
        }
    }

    // D2[od = ot*16 + 4q + r][t=l16] -> out[(b*TT+t)*32 + od], float4 per lane
#pragma unroll
    for (int s = 0; s < 2; ++s) {
        int t = t0 + s * 16 + l16;
        size_t ro = ((size_t)(b * TT + t)) * FOUT;
#pragma unroll
        for (int ot = 0; ot < 2; ++ot)
            *(f32x4*)(out + ro + ot * 16 + q * 4) = dacc[s][ot];
    }

    // Future rows 2048..2111 are copies of row 2047 (held by lanes l16==15
    // of the wave with t0==2016). Broadcast that row wave-internally via LDS,
    // then all 64 lanes fan the 64 duplicate rows out.
    if ((wave & 63) == 63) {
        float* fo = &fbc[w][0];
        if (l16 == 15) {
            *(f32x4*)(fo + q * 4)      = dacc[1][0];
            *(f32x4*)(fo + 16 + q * 4) = dacc[1][1];
        }
        asm volatile("s_waitcnt lgkmcnt(0)" ::: "memory");
        f32x4 r0 = *(const f32x4*)(fo + q * 4);
        f32x4 r1 = *(const f32x4*)(fo + 16 + q * 4);
#pragma unroll
        for (int fg = 0; fg < 4; ++fg) {
            int t = T_IN + fg * 16 + l16;
            size_t ro = ((size_t)(b * TT + t)) * FOUT;
            *(f32x4*)(out + ro + q * 4)      = r0;
            *(f32x4*)(out + ro + 16 + q * 4) = r1;
        }
    }
}

extern "C" void kernel_launch(void* const* d_in, const int* in_sizes, int n_in,
                              void* d_out, int out_size, void* d_ws, size_t ws_size,
                              hipStream_t stream) {
    const float* input = (const float*)d_in[0];
    const float* enc_W = (const float*)d_in[1];
    const float* enc_b = (const float*)d_in[2];
    const float* W_ih  = (const float*)d_in[3];
    // d_in[4] = W_hh: unused (h0 = 0 -> state_gates = b_hh only)
    const float* b_ih  = (const float*)d_in[5];
    const float* b_hh  = (const float*)d_in[6];
    const float* dec_W = (const float*)d_in[7];
    const float* dec_b = (const float*)d_in[8];
    // d_in[9] = future_n (fixed 64, baked into TT)

    _Float16* Mb    = (_Float16*)d_ws;
    float*    fb    = (float*)((char*)d_ws + WS_FB_OFF);
    _Float16* decWb = (_Float16*)((char*)d_ws + WS_DECW_OFF);
    float*    out   = (float*)d_out;

    prep2<<<776, 256, 0, stream>>>(enc_W, enc_b, W_ih, b_ih, b_hh, dec_W, Mb, fb, decWb);
    // 128 b * 2048 unique t rows / 32 rows-per-wave = 8192 waves; 4 waves/block
    // = 2048 blocks = exactly 8 blocks/CU (perfect balance)
    lstm_main<<<2048, 256, 0, stream>>>(input, Mb, fb, decWb, dec_b, out);
}

// Round 11
// 149.668 us; speedup vs baseline: 1.0218x; 1.0077x over previous
//
#include <hip/hip_runtime.h>

// EncoderDecoderLSTM fused kernel for MI355X (gfx950).
//
// Math: state never updates, h0=c0=0  =>
//   gates = input @ (W_ih @ enc_W)^T + (W_ih @ enc_b + b_ih + b_hh)
//   f-gate is dead (multiplies c0=0). Only i,g,o needed (768 of 1024 rows).
//
// prep2 pre-scales fused weights so MFMA emits exp2-ready gate values:
//     i,o rows x (-log2 e),  g rows x (2 log2 e)
//   U = exp2(iv), E = exp2(gv), Uo = exp2(ov)   (f32 exp2, exact args)
//   f32 reciprocals, UNMERGED (clamp-free; every saturation exact):
//     sigma(i) = rcp(1+U), tanh(g) = 1 - 2*rcp(1+E), sigma(o) = rcp(1+Uo)
//   tanh(c) via degree-11 odd poly, |c|<=1 -- PACKED f16
//   h = sigma(o) * tanh(c);  out = h @ dec_W^T + dec_b
//
// Round-11: REVERT TO BEST (R7 variant, 68.3us). The activation-variant
// table (R7 32-slot/68.3, R9 28-slot/70.5, R10 30-slot/69.1) shows slot
// count no longer correlates with time at the +-2-slot level -- the kernel
// is at a latency/issue plateau (VALUBusy ~64%, stall ~25us resistant to
// R5 pipelining / R7 LDS-delete / compiler scheduling). Lock in the best-
// measured formulation.
//
// Round-8 FAIL lesson: merged denominator overflows in f16 for live values.
// Round-6/7: LDS h-handoff eliminated via k-slot co-permutation of decWb
// and the activation output (MFMA k-sum is permutation-invariant).
// Round-5: 1-deep pipeline REGRESSED (VGPR 64->80) -- VGPR must stay <= 64.
// Round-4: packed-f16 poly tail (SIMD-32: f16x2 halves lane-cycles).
// Round-3: only 2048 unique t rows (future rows = copies of t=2047);
//   2048 blocks = exactly 8/CU, t0=2016 wave fans out the duplicates.
//
// prep2: block-per-row parallel weight fusion (768 rows, 32-iter loops).
// lstm_main: per-wave 32 rows, f16 MFMA 16x16x32; biases ride the MFMA C
//   operand; activation output feeds the decoder MFMA directly in registers.

typedef _Float16 f16x8 __attribute__((ext_vector_type(8)));
typedef _Float16 f16x4 __attribute__((ext_vector_type(4)));
typedef _Float16 f16x2 __attribute__((ext_vector_type(2)));
typedef float    f32x4 __attribute__((ext_vector_type(4)));
typedef float    f32x2 __attribute__((ext_vector_type(2)));
typedef __fp16   h16x2 __attribute__((ext_vector_type(2)));

#define T_IN 2048
#define TT   2112   // T + future_n
#define FIN  32
#define FOUT 32

// ws layout (bytes): Mb @0 (49152), fb @49152 (3072), decWb @52224 (16384)
#define WS_FB_OFF   49152
#define WS_DECW_OFF 52224

union PkU { h16x2 h; f16x2 f; unsigned u; };
union B2U { f16x8 v; unsigned u[4]; };

__global__ __launch_bounds__(256) void prep2(
    const float* __restrict__ enc_W, const float* __restrict__ enc_b,
    const float* __restrict__ W_ih, const float* __restrict__ b_ih,
    const float* __restrict__ b_hh, const float* __restrict__ dec_W,
    _Float16* __restrict__ Mb, float* __restrict__ fb, _Float16* __restrict__ decWb) {
    const int blk = blockIdx.x;
    const int tid = threadIdx.x;
    if (blk < 768) {
        // row gg: 0-255 = i (sg=gg), 256-511 = g (sg=gg+256), 512-767 = o
        const int gg = blk, sg = gg + (gg >= 256 ? 256 : 0);
        // exp2-ready prescale: i,o rows * -log2(e); g rows * 2*log2(e)
        const float SCL = (gg >= 256 && gg < 512) ?  2.8853900817779268f
                                                  : -1.4426950408889634f;
        const float* wr = W_ih + (size_t)sg * 256;
        const int f = tid & 31, r8 = tid >> 5;
        float acc = 0.f;
#pragma unroll
        for (int k = 0; k < 32; ++k) {
            int r = r8 * 32 + k;
            acc = fmaf(wr[r], enc_W[r * 32 + f], acc);
        }
        __shared__ float red[256];
        __shared__ float redb[256];
        __shared__ float red2[32];
        red[tid]  = acc;
        redb[tid] = wr[tid] * enc_b[tid];
        __syncthreads();
        if (tid < 32) {
            float s = 0.f;
#pragma unroll
            for (int k = 0; k < 8; ++k) s += red[k * 32 + tid];
            Mb[gg * 32 + tid] = (_Float16)(s * SCL);
        } else if (tid >= 128 && tid < 160) {
            int t2 = tid - 128;
            float s2 = 0.f;
#pragma unroll
            for (int k = 0; k < 8; ++k) s2 += redb[t2 * 8 + k];
            red2[t2] = s2;
        }
        __syncthreads();
        if (tid == 0) {
            float t = b_ih[sg] + b_hh[sg];
#pragma unroll
            for (int k = 0; k < 32; ++k) t += red2[k];
            fb[gg] = t * SCL;
        }
    } else {
        // blocks 768..775: dec_W f32 -> f16, PERMUTED within each 32-hid
        // block so the decoder B-operand is the activation output in its
        // natural register order: slot (q*8+j) <- hid (j<4 ? 4q+j
        // : 16+4q+j-4). Each thread's 4 slots map to 4 CONTIGUOUS source
        // hids, so the f32x4 load survives.
        int i  = (blk - 768) * 1024 + tid * 4;   // 4 consecutive slots
        int od = i >> 8, s = i & 255;
        int hb = s & 224, s32 = s & 31;
        int q  = s32 >> 3;
        int src = od * 256 + hb + 4 * q + ((s32 & 4) ? 16 : 0);
        f32x4 v = *(const f32x4*)(dec_W + src);
        f16x4 o;
#pragma unroll
        for (int j = 0; j < 4; ++j) o[j] = (_Float16)v[j];
        *(f16x4*)(decWb + i) = o;
    }
}

// Activation for a PAIR of adjacent h-values. f32 trans front-end (exact
// args, every saturation resolves via rcp(inf)=0, no clamps), packed-f16
// poly tail. Returns the packed f16x2 h as a u32. [R7 formulation -- the
// session's best-measured variant.]
__device__ __forceinline__ unsigned act_pair(f32x2 iv, f32x2 gv, f32x2 ov) {
    f32x2 U, E, Uo;
    U.x  = __builtin_amdgcn_exp2f(iv.x); U.y  = __builtin_amdgcn_exp2f(iv.y);
    E.x  = __builtin_amdgcn_exp2f(gv.x); E.y  = __builtin_amdgcn_exp2f(gv.y);
    Uo.x = __builtin_amdgcn_exp2f(ov.x); Uo.y = __builtin_amdgcn_exp2f(ov.y);
    f32x2 aU = U + 1.0f, aE = E + 1.0f, aUo = Uo + 1.0f;
    f32x2 rU, rE, rUo;
    rU.x  = __builtin_amdgcn_rcpf(aU.x);  rU.y  = __builtin_amdgcn_rcpf(aU.y);
    rE.x  = __builtin_amdgcn_rcpf(aE.x);  rE.y  = __builtin_amdgcn_rcpf(aE.y);
    rUo.x = __builtin_amdgcn_rcpf(aUo.x); rUo.y = __builtin_amdgcn_rcpf(aUo.y);
    f32x2 th = 1.0f - 2.0f * rE;      // tanh(g): all saturations exact
    f32x2 c  = th * rU;               // sigma(i)*tanh(g), |c|<1
    // ---- packed f16 tail ----
    PkU cu; cu.h = __builtin_amdgcn_cvt_pkrtz(c.x, c.y);
    PkU su; su.h = __builtin_amdgcn_cvt_pkrtz(rUo.x, rUo.y);   // sigma(o)
    f16x2 c16 = cu.f, so = su.f;
    f16x2 z  = c16 * c16;
    f16x2 cz = c16 * z;
    f16x2 P  = z * (_Float16)(-5.70498872745e-3f) + (_Float16)(2.06390887954e-2f);
    P = z * P + (_Float16)(-5.37397155531e-2f);
    P = z * P + (_Float16)(1.33314422036e-1f);
    P = z * P + (_Float16)(-3.33332819422e-1f);
    f16x2 tc = cz * P + c16;          // tanh(c)
    PkU r; r.f = so * tc;             // h = sigma(o)*tanh(c), packed f16x2
    return r.u;
}

__global__ __launch_bounds__(256) void lstm_main(
    const float* __restrict__ in, const _Float16* __restrict__ Mb,
    const float* __restrict__ fb, const _Float16* __restrict__ decWb,
    const float* __restrict__ dec_b, float* __restrict__ out) {
    // tiny per-wave broadcast buffer (future-row fan-out only)
    __shared__ float fbc[4][32];

    const int lane = threadIdx.x & 63;
    const int w    = threadIdx.x >> 6;
    const int l16  = lane & 15;
    const int q    = lane >> 4;
    const int wave = blockIdx.x * 4 + w;      // 0..8191
    const int b    = wave >> 6;                // 64 waves per batch row
    const int t0   = (wave & 63) * 32;         // 0..2016 (unique rows only)

    // Input B-fragments: B[k=q*8+j][n=l16] = input[b][t][q*8+j]  (t < 2048)
    f16x8 bfr[2];
#pragma unroll
    for (int s = 0; s < 2; ++s) {
        int t  = t0 + s * 16 + l16;
        const float* p = in + ((size_t)(b * T_IN + t)) * FIN + q * 8;
        f32x4 u0 = *(const f32x4*)(p);
        f32x4 u1 = *(const f32x4*)(p + 4);
        f16x8 v;
#pragma unroll
        for (int j = 0; j < 4; ++j) { v[j] = (_Float16)u0[j]; v[4 + j] = (_Float16)u1[j]; }
        bfr[s] = v;
    }

    // decoder acc starts at dec_b (rides the MFMA C operand)
    f32x4 dacc[2][2];
#pragma unroll
    for (int ot = 0; ot < 2; ++ot) {
        f32x4 db = *(const f32x4*)(dec_b + ot * 16 + q * 4);
        dacc[0][ot] = db; dacc[1][ot] = db;
    }

    for (int hc = 0; hc < 8; ++hc) {
        const int hb = hc * 32;
        // Gate weight A-frags + bias C-frags
        f16x8 afr[3][2];
        f32x4 fbv[3][2];
#pragma unroll
        for (int gt = 0; gt < 3; ++gt)
#pragma unroll
            for (int X = 0; X < 2; ++X) {
                int grow = gt * 256 + hb + X * 16;
                afr[gt][X] = *(const f16x8*)(Mb + (size_t)(grow + l16) * 32 + q * 8);
                fbv[gt][X] = *(const f32x4*)(fb + grow + q * 4);
            }
        // Decoder A-frags (hid-permuted layout): A2[m=ot*16+l16][slot q*8+j]
        f16x8 a2[2];
#pragma unroll
        for (int ot = 0; ot < 2; ++ot)
            a2[ot] = *(const f16x8*)(decWb + (size_t)(ot * 16 + l16) * 256 + hb + q * 8);

#pragma unroll
        for (int s = 0; s < 2; ++s) {
            // D[m = gate hid][n = t]; bias pre-loaded as C operand.
            // Values arrive pre-scaled: exp2-ready.
            f32x4 gi[2], gg[2], go[2];
#pragma unroll
            for (int X = 0; X < 2; ++X) {
                gi[X] = __builtin_amdgcn_mfma_f32_16x16x32_f16(afr[0][X], bfr[s], fbv[0][X], 0, 0, 0);
                gg[X] = __builtin_amdgcn_mfma_f32_16x16x32_f16(afr[1][X], bfr[s], fbv[1][X], 0, 0, 0);
                go[X] = __builtin_amdgcn_mfma_f32_16x16x32_f16(afr[2][X], bfr[s], fbv[2][X], 0, 0, 0);
            }
            // Activation output in production order IS the decoder B-frag
            // (decWb slot permutation): elems 0..3 = X=0 r=0..3 (hid 4q+r),
            // elems 4..7 = X=1 r=0..3 (hid 16+4q+r).
            B2U b2u;
#pragma unroll
            for (int X = 0; X < 2; ++X) {
                f32x2 i01 = { gi[X][0], gi[X][1] }, i23 = { gi[X][2], gi[X][3] };
                f32x2 g01 = { gg[X][0], gg[X][1] }, g23 = { gg[X][2], gg[X][3] };
                f32x2 o01 = { go[X][0], go[X][1] }, o23 = { go[X][2], go[X][3] };
                b2u.u[X * 2 + 0] = act_pair(i01, g01, o01);
                b2u.u[X * 2 + 1] = act_pair(i23, g23, o23);
            }
#pragma unroll
            for (int ot = 0; ot < 2; ++ot)
                dacc[s][ot] = __builtin_amdgcn_mfma_f32_16x16x32_f16(a2[ot], b2u.v, dacc[s][ot], 0, 0, 0);
        }
    }

    // D2[od = ot*16 + 4q + r][t=l16] -> out[(b*TT+t)*32 + od], float4 per lane
#pragma unroll
    for (int s = 0; s < 2; ++s) {
        int t = t0 + s * 16 + l16;
        size_t ro = ((size_t)(b * TT + t)) * FOUT;
#pragma unroll
        for (int ot = 0; ot < 2; ++ot)
            *(f32x4*)(out + ro + ot * 16 + q * 4) = dacc[s][ot];
    }

    // Future rows 2048..2111 are copies of row 2047 (held by lanes l16==15
    // of the wave with t0==2016). Broadcast that row wave-internally via LDS,
    // then all 64 lanes fan the 64 duplicate rows out.
    if ((wave & 63) == 63) {
        float* fo = &fbc[w][0];
        if (l16 == 15) {
            *(f32x4*)(fo + q * 4)      = dacc[1][0];
            *(f32x4*)(fo + 16 + q * 4) = dacc[1][1];
        }
        asm volatile("s_waitcnt lgkmcnt(0)" ::: "memory");
        f32x4 r0 = *(const f32x4*)(fo + q * 4);
        f32x4 r1 = *(const f32x4*)(fo + 16 + q * 4);
#pragma unroll
        for (int fg = 0; fg < 4; ++fg) {
            int t = T_IN + fg * 16 + l16;
            size_t ro = ((size_t)(b * TT + t)) * FOUT;
            *(f32x4*)(out + ro + q * 4)      = r0;
            *(f32x4*)(out + ro + 16 + q * 4) = r1;
        }
    }
}

extern "C" void kernel_launch(void* const* d_in, const int* in_sizes, int n_in,
                              void* d_out, int out_size, void* d_ws, size_t ws_size,
                              hipStream_t stream) {
    const float* input = (const float*)d_in[0];
    const float* enc_W = (const float*)d_in[1];
    const float* enc_b = (const float*)d_in[2];
    const float* W_ih  = (const float*)d_in[3];
    // d_in[4] = W_hh: unused (h0 = 0 -> state_gates = b_hh only)
    const float* b_ih  = (const float*)d_in[5];
    const float* b_hh  = (const float*)d_in[6];
    const float* dec_W = (const float*)d_in[7];
    const float* dec_b = (const float*)d_in[8];
    // d_in[9] = future_n (fixed 64, baked into TT)

    _Float16* Mb    = (_Float16*)d_ws;
    float*    fb    = (float*)((char*)d_ws + WS_FB_OFF);
    _Float16* decWb = (_Float16*)((char*)d_ws + WS_DECW_OFF);
    float*    out   = (float*)d_out;

    prep2<<<776, 256, 0, stream>>>(enc_W, enc_b, W_ih, b_ih, b_hh, dec_W, Mb, fb, decWb);
    // 128 b * 2048 unique t rows / 32 rows-per-wave = 8192 waves; 4 waves/block
    // = 2048 blocks = exactly 8 blocks/CU (perfect balance)
    lstm_main<<<2048, 256, 0, stream>>>(input, Mb, fb, decWb, dec_b, out);
}